// Round 3
// baseline (815.510 us; speedup 1.0000x reference)
//
#include <hip/hip_runtime.h>

// WKV7 recurrence, T=4096, H=32, N=64, fp32. One wave per state row.
// R8 post-mortem: paired DPP reduce helped (680->584us, VALU 48->56%) but the
// reduce is still on the state-update critical path (s_t -> reduce -> sa ->
// s_{t+1}): ~60cy serial per step. R9: algebraic decoupling. Expand
//   sa_{t+1} = Qa_t + sa_t*BA_t + v_t*KA_t,  Qa_t = sum(s_{t-1} * w_t*a_{t+1})
//   x_t      = Qr_t + sa_t*BR_t + v_t*KR_t,  Qr_t = sum(s_{t-1} * w_t*r_t)
// so the reductions run over s_{t-1} (one step of slack; pipeline depth 2) and
// the serial chains are 1 FMA/step each. BA/KA/BR/KR are input-only scalars:
// computed by a pre-pass kernel into d_ws (2MB, [h][t][4]), staged per chunk,
// read via broadcast ds_read_b128. a is staged shifted by one step (SRD OOB
// returns 0) -> uniform 16-step loop, no chunk-boundary special case.

static constexpr int T_LEN = 4096;
static constexpr int H_HEADS = 32;
static constexpr int N_DIM = 64;
static constexpr int HN = H_HEADS * N_DIM;                 // 2048
static constexpr int WPB = 8;                              // waves/block
static constexpr int BT = WPB * 64;                        // 512 threads
static constexpr int NB = (H_HEADS * N_DIM) / WPB;         // 256 blocks
static constexpr int C = 16;                               // steps/chunk
static constexpr int TC = T_LEN / C;                       // 256 chunks

// ---- raw buffer load: SGPR soffset, OOB-safe (returns 0) ----
typedef int int32x4_t __attribute__((ext_vector_type(4)));
__device__ float llvm_amdgcn_raw_buffer_load_fp32(int32x4_t srsrc, int voffset,
                                                  int soffset, int glc_slc)
    __asm("llvm.amdgcn.raw.buffer.load.f32");

__device__ __forceinline__ int32x4_t make_srd(const void* p, unsigned bytes) {
  int32x4_t r;
  r.x = (int)(unsigned long long)p;
  r.y = (int)((unsigned long long)p >> 32); // stride=0 -> raw
  r.z = (int)bytes;                         // num_records
  r.w = 0x00020000;                         // raw dword
  return r;
}

// ---- 64-lane sum, single chain (prologue only) ----
__device__ __forceinline__ float wave_sum_bcast(float x) {
  asm volatile(
      "s_nop 1\n\t"
      "v_add_f32 %0, %0, %0 row_shr:1 bound_ctrl:0\n\t"
      "s_nop 1\n\t"
      "v_add_f32 %0, %0, %0 row_shr:2 bound_ctrl:0\n\t"
      "s_nop 1\n\t"
      "v_add_f32 %0, %0, %0 row_shr:4 bound_ctrl:0\n\t"
      "s_nop 1\n\t"
      "v_add_f32 %0, %0, %0 row_shr:8 bound_ctrl:0\n\t"
      "s_nop 1\n\t"
      "v_add_f32 %0, %0, %0 row_bcast:15 row_mask:0xa\n\t"
      "s_nop 1\n\t"
      "v_add_f32 %0, %0, %0 row_bcast:31 row_mask:0xc\n\t"
      "s_nop 1\n\t"
      : "+v"(x));
  return __int_as_float(__builtin_amdgcn_readlane(__float_as_int(x), 63));
}

// ---- paired 64-lane sums: two independent chains interleaved so each DPP
// op (+ s_nop 0) covers the other chain's 2-wait-state DPP hazard. Result
// (full sum) valid in lane 63 of each operand. ----
__device__ __forceinline__ void wave_sum2(float& x, float& y) {
  asm volatile(
      "s_nop 1\n\t"
      "v_add_f32 %0, %0, %0 row_shr:1 bound_ctrl:0\n\t"
      "v_add_f32 %1, %1, %1 row_shr:1 bound_ctrl:0\n\t"
      "s_nop 0\n\t"
      "v_add_f32 %0, %0, %0 row_shr:2 bound_ctrl:0\n\t"
      "v_add_f32 %1, %1, %1 row_shr:2 bound_ctrl:0\n\t"
      "s_nop 0\n\t"
      "v_add_f32 %0, %0, %0 row_shr:4 bound_ctrl:0\n\t"
      "v_add_f32 %1, %1, %1 row_shr:4 bound_ctrl:0\n\t"
      "s_nop 0\n\t"
      "v_add_f32 %0, %0, %0 row_shr:8 bound_ctrl:0\n\t"
      "v_add_f32 %1, %1, %1 row_shr:8 bound_ctrl:0\n\t"
      "s_nop 0\n\t"
      "v_add_f32 %0, %0, %0 row_bcast:15 row_mask:0xa\n\t"
      "v_add_f32 %1, %1, %1 row_bcast:15 row_mask:0xa\n\t"
      "s_nop 0\n\t"
      "v_add_f32 %0, %0, %0 row_bcast:31 row_mask:0xc\n\t"
      "v_add_f32 %1, %1, %1 row_bcast:31 row_mask:0xc\n\t"
      "s_nop 1\n\t"
      : "+v"(x), "+v"(y));
}

// ---- pre-pass: input-only cross scalars per (h,t):
//   BA = sum(b_t*a_{t+1}), KA = sum(k_t*a_{t+1}),
//   BR = sum(b_t*r_t),     KR = sum(k_t*r_t)   -> scw[h][t][4]
__global__ __launch_bounds__(256) void wkv7_pre(
    const float* __restrict__ rp, const float* __restrict__ kp,
    const float* __restrict__ ap, const float* __restrict__ bp,
    float* __restrict__ scw) {
  const int tid  = threadIdx.x;
  const int lane = tid & 63;
  const int wv   = tid >> 6;
  const int wid  = blockIdx.x * 4 + wv;     // 0..T*H-1
  const int t    = wid >> 5;                // 0..4095
  const int h    = wid & 31;
  const int hb   = h * N_DIM;

  constexpr unsigned ARR_BYTES = (unsigned)T_LEN * HN * 4u;
  const int32x4_t srd_r = make_srd(rp, ARR_BYTES);
  const int32x4_t srd_k = make_srd(kp, ARR_BYTES);
  const int32x4_t srd_a = make_srd(ap, ARR_BYTES);
  const int32x4_t srd_b = make_srd(bp, ARR_BYTES);

  const int vo    = lane << 2;
  const int so_t  = (t * HN + hb) << 2;
  const int so_t1 = ((t + 1) * HN + hb) << 2;   // t=T-1 -> OOB -> 0

  const float bv = llvm_amdgcn_raw_buffer_load_fp32(srd_b, vo, so_t, 0);
  const float kv = llvm_amdgcn_raw_buffer_load_fp32(srd_k, vo, so_t, 0);
  const float rv = llvm_amdgcn_raw_buffer_load_fp32(srd_r, vo, so_t, 0);
  const float a1 = llvm_amdgcn_raw_buffer_load_fp32(srd_a, vo, so_t1, 0);

  float pba = bv * a1, pka = kv * a1;
  float pbr = bv * rv, pkr = kv * rv;
  wave_sum2(pba, pka);
  wave_sum2(pbr, pkr);
  if (lane == 63) {
    float4 o;
    o.x = pba; o.y = pka; o.z = pbr; o.w = pkr;
    *(float4*)(scw + ((size_t)h * T_LEN + t) * 4) = o;
  }
}

__global__ __launch_bounds__(BT, 2) void wkv7_scan(
    const float* __restrict__ rp, const float* __restrict__ wp,
    const float* __restrict__ kp, const float* __restrict__ vp,
    const float* __restrict__ ap, const float* __restrict__ bp,
    const float* __restrict__ s0p, float* __restrict__ xp,
    float* __restrict__ sop, const float* __restrict__ scp) {
  const int tid  = threadIdx.x;
  const int lane = tid & 63;
  const int wv   = tid >> 6;
  const int blk  = blockIdx.x;
  const int h     = blk & (H_HEADS - 1);
  const int ibase = (blk >> 5) * WPB;
  const int i     = ibase + wv;
  const int hb    = h * N_DIM;

  // [buf][step][channel]: read addr = lane*4 + imm -> conflict-free.
  // sA holds a SHIFTED one step: sA[bi][u] = a[c*16+u+1].
  __shared__ float sw[2][C][N_DIM], sA[2][C][N_DIM], sB[2][C][N_DIM],
                   sK[2][C][N_DIM], sR[2][C][N_DIM];
  __shared__ float sV[2][C][WPB];
  __shared__ __align__(16) float sSC[2][C * 4];   // {BA,KA,BR,KR} per step
  __shared__ float xbuf[WPB][65];

  constexpr unsigned ARR_BYTES = (unsigned)T_LEN * HN * 4u;
  constexpr unsigned SC_BYTES  = (unsigned)T_LEN * H_HEADS * 4u * 4u; // 2MB
  const int32x4_t srd_r = make_srd(rp, ARR_BYTES);
  const int32x4_t srd_w = make_srd(wp, ARR_BYTES);
  const int32x4_t srd_k = make_srd(kp, ARR_BYTES);
  const int32x4_t srd_v = make_srd(vp, ARR_BYTES);
  const int32x4_t srd_a = make_srd(ap, ARR_BYTES);
  const int32x4_t srd_b = make_srd(bp, ARR_BYTES);
  const int32x4_t srd_c = make_srd(scp, SC_BYTES);

  float s = s0p[(size_t)(hb + i) * N_DIM + lane];
  const float a0v = ap[hb + lane];               // a_0 for the sa_0 prologue

  // staging index map: thread covers (u0, j) and (u0+8, j) for 5 arrays
  const int j   = lane;
  const int u0  = tid >> 6;                       // 0..7
  const int vo0 = (u0 * HN + j) << 2;             // pass 0 voffset (bytes)
  const int vo1 = vo0 + (8 * HN << 2);            // pass 1
  const int sbase = hb << 2;
  // v staging: waves 0-1 (tid<128): u=tid>>3 (0..15), q=tid&7
  const int uv  = tid >> 3;
  const int qv  = tid & 7;
  const int vov = (uv * HN + qv) << 2;
  const int svbase = (hb + ibase) << 2;
  // sc staging: wave 2, 64 contiguous floats per chunk from scw[h][c*16..]
  const int voc = lane << 2;
  const int scbase = h * (T_LEN * 16);            // bytes: h*T*4floats*4B

  float g0, g1, g2, g3, g4, g5, g6, g7, g8, g9, g10, g11;

#define STAGE_LOAD(CI)                                                   \
  do {                                                                   \
    const int so = (CI) * (C * HN * 4) + sbase;                          \
    g0 = llvm_amdgcn_raw_buffer_load_fp32(srd_w, vo0, so, 0);            \
    g1 = llvm_amdgcn_raw_buffer_load_fp32(srd_a, vo0, so + (HN << 2), 0);\
    g2 = llvm_amdgcn_raw_buffer_load_fp32(srd_b, vo0, so, 0);            \
    g3 = llvm_amdgcn_raw_buffer_load_fp32(srd_k, vo0, so, 0);            \
    g4 = llvm_amdgcn_raw_buffer_load_fp32(srd_r, vo0, so, 0);            \
    g5 = llvm_amdgcn_raw_buffer_load_fp32(srd_w, vo1, so, 0);            \
    g6 = llvm_amdgcn_raw_buffer_load_fp32(srd_a, vo1, so + (HN << 2), 0);\
    g7 = llvm_amdgcn_raw_buffer_load_fp32(srd_b, vo1, so, 0);            \
    g8 = llvm_amdgcn_raw_buffer_load_fp32(srd_k, vo1, so, 0);            \
    g9 = llvm_amdgcn_raw_buffer_load_fp32(srd_r, vo1, so, 0);            \
    if (wv < 2)                                                          \
      g10 = llvm_amdgcn_raw_buffer_load_fp32(                            \
          srd_v, vov, (CI) * (C * HN * 4) + svbase, 0);                  \
    if (wv == 2)                                                         \
      g11 = llvm_amdgcn_raw_buffer_load_fp32(                            \
          srd_c, voc, (CI) * (C * 16) + scbase, 0);                      \
  } while (0)

#define STAGE_STORE(BI)                                                  \
  do {                                                                   \
    sw[BI][u0][j] = g0;  sA[BI][u0][j] = g1;  sB[BI][u0][j] = g2;        \
    sK[BI][u0][j] = g3;  sR[BI][u0][j] = g4;                             \
    sw[BI][u0 + 8][j] = g5;  sA[BI][u0 + 8][j] = g6;                     \
    sB[BI][u0 + 8][j] = g7;  sK[BI][u0 + 8][j] = g8;                     \
    sR[BI][u0 + 8][j] = g9;                                              \
    if (wv < 2) sV[BI][uv][qv] = g10;                                    \
    if (wv == 2) sSC[BI][lane] = g11;                                    \
  } while (0)

  float xacc = 0.0f;

  STAGE_LOAD(0);
  STAGE_STORE(0);
  // prologue: sa_0 = sum(s_init * a_0) — only unpaired reduction
  float sa;
  {
    float p0 = s * a0v;
    sa = wave_sum_bcast(p0);
  }
  __syncthreads();

  for (int c = 0; c < TC; ++c) {
    const int bi = c & 1;

    STAGE_LOAD(c + 1);              // global loads fly under compute
    __builtin_amdgcn_sched_barrier(0);

    // one-step LDS prefetch; la = a_{t+1} (shifted staging)
    float lw = sw[bi][0][lane], la = sA[bi][0][lane], lb = sB[bi][0][lane],
          lk = sK[bi][0][lane], lr = sR[bi][0][lane], lv = sV[bi][0][wv];
    float4 scv = *(const float4*)&sSC[bi][0];
#pragma unroll
    for (int u = 0; u < C; ++u) {
      const int un = (u < C - 1) ? u + 1 : u;  // compile-time per iter
      const float nw = sw[bi][un][lane], na = sA[bi][un][lane],
                  nb = sB[bi][un][lane], nk = sK[bi][un][lane],
                  nr = sR[bi][un][lane], nv = sV[bi][un][wv];
      const float4 nscv = *(const float4*)&sSC[bi][un * 4];

      // reductions over s_{t-1} (pre-update state) — off the critical path
      const float wa = lw * la;     // w_t * a_{t+1}
      const float wr = lw * lr;     // w_t * r_t
      float pq = s * wa;            // -> Qa_t
      float px = s * wr;            // -> Qr_t
      wave_sum2(pq, px);
      const float Qa =
          __int_as_float(__builtin_amdgcn_readlane(__float_as_int(pq), 63));
      const float Qr =
          __int_as_float(__builtin_amdgcn_readlane(__float_as_int(px), 63));

      // state update uses sa_t (already in hand): 1-deep s-chain
      s = fmaf(s, lw, fmaf(sa, lb, lv * lk));

      // x_t and sa_{t+1} via scalar recomposition (1-deep sa-chain)
      const float xv = fmaf(sa, scv.z, fmaf(lv, scv.w, Qr));
      sa             = fmaf(sa, scv.x, fmaf(lv, scv.y, Qa));

      const int tl = ((c & 3) << 4) | u;
      xacc = (lane == tl) ? xv : xacc;

      lw = nw; la = na; lb = nb; lk = nk; lr = nr; lv = nv; scv = nscv;
    }

    __builtin_amdgcn_sched_barrier(0);
    STAGE_STORE(bi ^ 1);            // vmcnt wait lands here, after compute
    __syncthreads();

    if ((c & 3) == 3) {
      // 64 steps complete: transpose through LDS -> coalesced stores
      xbuf[wv][lane] = xacc;
      __syncthreads();
      const int tl2 = tid >> 3;
      const int iw  = tid & 7;
      const int t0  = (c + 1) * C - 64;
      xp[(size_t)(t0 + tl2) * HN + hb + ibase + iw] = xbuf[iw][tl2];
      // no trailing barrier needed: next xbuf write is 4 chunk-barriers away
    }
  }

#undef STAGE_LOAD
#undef STAGE_STORE

  sop[(size_t)(hb + i) * N_DIM + lane] = s;
}

extern "C" void kernel_launch(void* const* d_in, const int* in_sizes, int n_in,
                              void* d_out, int out_size, void* d_ws, size_t ws_size,
                              hipStream_t stream) {
  // setup_inputs order: seq_length(int,1), r, w, k, v, a, b, state2
  const float* r  = (const float*)d_in[1];
  const float* w  = (const float*)d_in[2];
  const float* k  = (const float*)d_in[3];
  const float* v  = (const float*)d_in[4];
  const float* a  = (const float*)d_in[5];
  const float* b  = (const float*)d_in[6];
  const float* s0 = (const float*)d_in[7];
  float* x    = (float*)d_out;                       // [T,H,1,N] flat
  float* sout = x + (size_t)T_LEN * H_HEADS * N_DIM; // [H,N,N]
  float* scw  = (float*)d_ws;                        // 2MB: [H][T][4] scalars

  wkv7_pre<<<dim3(T_LEN * H_HEADS / 4), dim3(256), 0, stream>>>(r, k, a, b, scw);
  wkv7_scan<<<dim3(NB), dim3(BT), 0, stream>>>(r, w, k, v, a, b, s0, x, sout, scw);
}

// Round 4
// 795.071 us; speedup vs baseline: 1.0257x; 1.0257x over previous
//
#include <hip/hip_runtime.h>

// WKV7 recurrence, T=4096, H=32, N=64, fp32. One wave per state row.
// R9 post-mortem: algebraic decoupling (sa_{t+1} = Qa_t + sa_t*BA_t + v_t*KA_t
// with Qa_t reduced over s_{t-1}) was correct but the reduce was consumed in
// the SAME iteration it was issued -> on an in-order wave all recomposition
// ops chained onto the DPP block (584->691us). R10: software-pipeline by one
// iteration. Body t: [issue reduce_t over s_{t-1}] [consume reduce_{t-1},
// issued a full iteration ago -> readlane stall-free -> sa_t, x_{t-1}]
// [state update s_t]. Two reduces in flight (qpq/qpx carried vs npq/npx
// fresh). Chunk epilogue drains the last reduce before the staging barrier
// so the x-store grouping is unchanged. w*a and w*r pre-multiplied in the
// off-path prefetch. Arithmetic identical to R9 -> same results.

static constexpr int T_LEN = 4096;
static constexpr int H_HEADS = 32;
static constexpr int N_DIM = 64;
static constexpr int HN = H_HEADS * N_DIM;                 // 2048
static constexpr int WPB = 8;                              // waves/block
static constexpr int BT = WPB * 64;                        // 512 threads
static constexpr int NB = (H_HEADS * N_DIM) / WPB;         // 256 blocks
static constexpr int C = 16;                               // steps/chunk
static constexpr int TC = T_LEN / C;                       // 256 chunks

// ---- raw buffer load: SGPR soffset, OOB-safe (returns 0) ----
typedef int int32x4_t __attribute__((ext_vector_type(4)));
__device__ float llvm_amdgcn_raw_buffer_load_fp32(int32x4_t srsrc, int voffset,
                                                  int soffset, int glc_slc)
    __asm("llvm.amdgcn.raw.buffer.load.f32");

__device__ __forceinline__ int32x4_t make_srd(const void* p, unsigned bytes) {
  int32x4_t r;
  r.x = (int)(unsigned long long)p;
  r.y = (int)((unsigned long long)p >> 32); // stride=0 -> raw
  r.z = (int)bytes;                         // num_records
  r.w = 0x00020000;                         // raw dword
  return r;
}

// ---- 64-lane sum, single chain (prologue only) ----
__device__ __forceinline__ float wave_sum_bcast(float x) {
  asm volatile(
      "s_nop 1\n\t"
      "v_add_f32 %0, %0, %0 row_shr:1 bound_ctrl:0\n\t"
      "s_nop 1\n\t"
      "v_add_f32 %0, %0, %0 row_shr:2 bound_ctrl:0\n\t"
      "s_nop 1\n\t"
      "v_add_f32 %0, %0, %0 row_shr:4 bound_ctrl:0\n\t"
      "s_nop 1\n\t"
      "v_add_f32 %0, %0, %0 row_shr:8 bound_ctrl:0\n\t"
      "s_nop 1\n\t"
      "v_add_f32 %0, %0, %0 row_bcast:15 row_mask:0xa\n\t"
      "s_nop 1\n\t"
      "v_add_f32 %0, %0, %0 row_bcast:31 row_mask:0xc\n\t"
      "s_nop 1\n\t"
      : "+v"(x));
  return __int_as_float(__builtin_amdgcn_readlane(__float_as_int(x), 63));
}

// ---- paired 64-lane sums: two independent chains interleaved so each DPP
// op (+ s_nop 0) covers the other chain's 2-wait-state DPP hazard. Result
// (full sum) valid in lane 63 of each operand. ----
__device__ __forceinline__ void wave_sum2(float& x, float& y) {
  asm volatile(
      "s_nop 1\n\t"
      "v_add_f32 %0, %0, %0 row_shr:1 bound_ctrl:0\n\t"
      "v_add_f32 %1, %1, %1 row_shr:1 bound_ctrl:0\n\t"
      "s_nop 0\n\t"
      "v_add_f32 %0, %0, %0 row_shr:2 bound_ctrl:0\n\t"
      "v_add_f32 %1, %1, %1 row_shr:2 bound_ctrl:0\n\t"
      "s_nop 0\n\t"
      "v_add_f32 %0, %0, %0 row_shr:4 bound_ctrl:0\n\t"
      "v_add_f32 %1, %1, %1 row_shr:4 bound_ctrl:0\n\t"
      "s_nop 0\n\t"
      "v_add_f32 %0, %0, %0 row_shr:8 bound_ctrl:0\n\t"
      "v_add_f32 %1, %1, %1 row_shr:8 bound_ctrl:0\n\t"
      "s_nop 0\n\t"
      "v_add_f32 %0, %0, %0 row_bcast:15 row_mask:0xa\n\t"
      "v_add_f32 %1, %1, %1 row_bcast:15 row_mask:0xa\n\t"
      "s_nop 0\n\t"
      "v_add_f32 %0, %0, %0 row_bcast:31 row_mask:0xc\n\t"
      "v_add_f32 %1, %1, %1 row_bcast:31 row_mask:0xc\n\t"
      "s_nop 1\n\t"
      : "+v"(x), "+v"(y));
}

// ---- pre-pass: input-only cross scalars per (h,t):
//   BA = sum(b_t*a_{t+1}), KA = sum(k_t*a_{t+1}),
//   BR = sum(b_t*r_t),     KR = sum(k_t*r_t)   -> scw[h][t][4]
__global__ __launch_bounds__(256) void wkv7_pre(
    const float* __restrict__ rp, const float* __restrict__ kp,
    const float* __restrict__ ap, const float* __restrict__ bp,
    float* __restrict__ scw) {
  const int tid  = threadIdx.x;
  const int lane = tid & 63;
  const int wv   = tid >> 6;
  const int wid  = blockIdx.x * 4 + wv;     // 0..T*H-1
  const int t    = wid >> 5;                // 0..4095
  const int h    = wid & 31;
  const int hb   = h * N_DIM;

  constexpr unsigned ARR_BYTES = (unsigned)T_LEN * HN * 4u;
  const int32x4_t srd_r = make_srd(rp, ARR_BYTES);
  const int32x4_t srd_k = make_srd(kp, ARR_BYTES);
  const int32x4_t srd_a = make_srd(ap, ARR_BYTES);
  const int32x4_t srd_b = make_srd(bp, ARR_BYTES);

  const int vo    = lane << 2;
  const int so_t  = (t * HN + hb) << 2;
  const int so_t1 = ((t + 1) * HN + hb) << 2;   // t=T-1 -> OOB -> 0

  const float bv = llvm_amdgcn_raw_buffer_load_fp32(srd_b, vo, so_t, 0);
  const float kv = llvm_amdgcn_raw_buffer_load_fp32(srd_k, vo, so_t, 0);
  const float rv = llvm_amdgcn_raw_buffer_load_fp32(srd_r, vo, so_t, 0);
  const float a1 = llvm_amdgcn_raw_buffer_load_fp32(srd_a, vo, so_t1, 0);

  float pba = bv * a1, pka = kv * a1;
  float pbr = bv * rv, pkr = kv * rv;
  wave_sum2(pba, pka);
  wave_sum2(pbr, pkr);
  if (lane == 63) {
    float4 o;
    o.x = pba; o.y = pka; o.z = pbr; o.w = pkr;
    *(float4*)(scw + ((size_t)h * T_LEN + t) * 4) = o;
  }
}

__global__ __launch_bounds__(BT, 2) void wkv7_scan(
    const float* __restrict__ rp, const float* __restrict__ wp,
    const float* __restrict__ kp, const float* __restrict__ vp,
    const float* __restrict__ ap, const float* __restrict__ bp,
    const float* __restrict__ s0p, float* __restrict__ xp,
    float* __restrict__ sop, const float* __restrict__ scp_g) {
  const int tid  = threadIdx.x;
  const int lane = tid & 63;
  const int wv   = tid >> 6;
  const int blk  = blockIdx.x;
  const int h     = blk & (H_HEADS - 1);
  const int ibase = (blk >> 5) * WPB;
  const int i     = ibase + wv;
  const int hb    = h * N_DIM;

  // [buf][step][channel]: read addr = lane*4 + imm -> conflict-free.
  // sA holds a SHIFTED one step: sA[bi][u] = a[c*16+u+1].
  __shared__ float sw[2][C][N_DIM], sA[2][C][N_DIM], sB[2][C][N_DIM],
                   sK[2][C][N_DIM], sR[2][C][N_DIM];
  __shared__ float sV[2][C][WPB];
  __shared__ __align__(16) float sSC[2][C * 4];   // {BA,KA,BR,KR} per step
  __shared__ float xbuf[WPB][65];

  constexpr unsigned ARR_BYTES = (unsigned)T_LEN * HN * 4u;
  constexpr unsigned SC_BYTES  = (unsigned)T_LEN * H_HEADS * 4u * 4u; // 2MB
  const int32x4_t srd_r = make_srd(rp, ARR_BYTES);
  const int32x4_t srd_w = make_srd(wp, ARR_BYTES);
  const int32x4_t srd_k = make_srd(kp, ARR_BYTES);
  const int32x4_t srd_v = make_srd(vp, ARR_BYTES);
  const int32x4_t srd_a = make_srd(ap, ARR_BYTES);
  const int32x4_t srd_b = make_srd(bp, ARR_BYTES);
  const int32x4_t srd_c = make_srd(scp_g, SC_BYTES);

  float s = s0p[(size_t)(hb + i) * N_DIM + lane];
  const float a0v = ap[hb + lane];               // a_0 for the sa_0 prologue

  // staging index map: thread covers (u0, j) and (u0+8, j) for 5 arrays
  const int j   = lane;
  const int u0  = tid >> 6;                       // 0..7
  const int vo0 = (u0 * HN + j) << 2;             // pass 0 voffset (bytes)
  const int vo1 = vo0 + (8 * HN << 2);            // pass 1
  const int sbase = hb << 2;
  // v staging: waves 0-1 (tid<128): u=tid>>3 (0..15), q=tid&7
  const int uv  = tid >> 3;
  const int qv  = tid & 7;
  const int vov = (uv * HN + qv) << 2;
  const int svbase = (hb + ibase) << 2;
  // sc staging: wave 2, 64 contiguous floats per chunk from scw[h][c*16..]
  const int voc = lane << 2;
  const int scbase = h * (T_LEN * 16);            // bytes: h*T*4floats*4B

  float g0, g1, g2, g3, g4, g5, g6, g7, g8, g9, g10, g11;

#define STAGE_LOAD(CI)                                                   \
  do {                                                                   \
    const int so = (CI) * (C * HN * 4) + sbase;                          \
    g0 = llvm_amdgcn_raw_buffer_load_fp32(srd_w, vo0, so, 0);            \
    g1 = llvm_amdgcn_raw_buffer_load_fp32(srd_a, vo0, so + (HN << 2), 0);\
    g2 = llvm_amdgcn_raw_buffer_load_fp32(srd_b, vo0, so, 0);            \
    g3 = llvm_amdgcn_raw_buffer_load_fp32(srd_k, vo0, so, 0);            \
    g4 = llvm_amdgcn_raw_buffer_load_fp32(srd_r, vo0, so, 0);            \
    g5 = llvm_amdgcn_raw_buffer_load_fp32(srd_w, vo1, so, 0);            \
    g6 = llvm_amdgcn_raw_buffer_load_fp32(srd_a, vo1, so + (HN << 2), 0);\
    g7 = llvm_amdgcn_raw_buffer_load_fp32(srd_b, vo1, so, 0);            \
    g8 = llvm_amdgcn_raw_buffer_load_fp32(srd_k, vo1, so, 0);            \
    g9 = llvm_amdgcn_raw_buffer_load_fp32(srd_r, vo1, so, 0);            \
    if (wv < 2)                                                          \
      g10 = llvm_amdgcn_raw_buffer_load_fp32(                            \
          srd_v, vov, (CI) * (C * HN * 4) + svbase, 0);                  \
    if (wv == 2)                                                         \
      g11 = llvm_amdgcn_raw_buffer_load_fp32(                            \
          srd_c, voc, (CI) * (C * 16) + scbase, 0);                      \
  } while (0)

#define STAGE_STORE(BI)                                                  \
  do {                                                                   \
    sw[BI][u0][j] = g0;  sA[BI][u0][j] = g1;  sB[BI][u0][j] = g2;        \
    sK[BI][u0][j] = g3;  sR[BI][u0][j] = g4;                             \
    sw[BI][u0 + 8][j] = g5;  sA[BI][u0 + 8][j] = g6;                     \
    sB[BI][u0 + 8][j] = g7;  sK[BI][u0 + 8][j] = g8;                     \
    sR[BI][u0 + 8][j] = g9;                                              \
    if (wv < 2) sV[BI][uv][qv] = g10;                                    \
    if (wv == 2) sSC[BI][lane] = g11;                                    \
  } while (0)

  float xacc = 0.0f;

  STAGE_LOAD(0);
  STAGE_STORE(0);
  // prologue: sa_0 = sum(s_init * a_0) — only unpaired reduction
  float sa;
  {
    float p0 = s * a0v;
    sa = wave_sum_bcast(p0);
  }
  __syncthreads();

  // in-flight reduce regs (consumed one iteration after issue) + their
  // recomposition operands
  float qpq = 0.0f, qpx = 0.0f;
  float lvp = 0.0f;
  float4 scp;
  scp.x = scp.y = scp.z = scp.w = 0.0f;

  for (int c = 0; c < TC; ++c) {
    const int bi = c & 1;

    STAGE_LOAD(c + 1);              // global loads fly under compute
    __builtin_amdgcn_sched_barrier(0);

    // one-step LDS prefetch; wa = w_t*a_{t+1}, wr = w_t*r_t premultiplied
    // off the carried path.
    float lw = sw[bi][0][lane];
    float lb = sB[bi][0][lane], lk = sK[bi][0][lane];
    float lv = sV[bi][0][wv];
    float lwa = lw * sA[bi][0][lane];
    float lwr = lw * sR[bi][0][lane];
    float4 scv = *(const float4*)&sSC[bi][0];
#pragma unroll
    for (int u = 0; u < C; ++u) {
      const int un = (u < C - 1) ? u + 1 : u;  // compile-time per iter
      const float nw = sw[bi][un][lane];
      const float nwa = nw * sA[bi][un][lane];
      const float nwr = nw * sR[bi][un][lane];
      const float nb = sB[bi][un][lane], nk = sK[bi][un][lane],
                  nv = sV[bi][un][wv];
      const float4 nscv = *(const float4*)&sSC[bi][un * 4];

      // 1. issue reduce_t over s_{t-1} (s not yet updated this iter)
      float npq = s * lwa;          // -> Qa_t
      float npx = s * lwr;          // -> Qr_t
      wave_sum2(npq, npx);

      // 2. consume reduce_{t-1} (issued a full iteration ago; no stall)
      if (u >= 1) {
        const float Qa =
            __int_as_float(__builtin_amdgcn_readlane(__float_as_int(qpq), 63));
        const float Qr =
            __int_as_float(__builtin_amdgcn_readlane(__float_as_int(qpx), 63));
        const float xv = fmaf(sa, scp.z, fmaf(lvp, scp.w, Qr)); // x_{t-1}
        sa             = fmaf(sa, scp.x, fmaf(lvp, scp.y, Qa)); // sa_t
        const int tl = ((c & 3) << 4) | (u - 1);
        xacc = (lane == tl) ? xv : xacc;
      }
      // (u==0: sa_t already produced by previous chunk's epilogue / prologue)

      // 3. state update s_t (1-deep chain from sa_t)
      s = fmaf(s, lw, fmaf(sa, lb, lv * lk));

      qpq = npq; qpx = npx; lvp = lv; scp = scv;
      lw = nw; lwa = nwa; lwr = nwr; lb = nb; lk = nk; lv = nv; scv = nscv;
    }

    // chunk epilogue: drain reduce for t = c*16+15 (keeps x-store grouping)
    {
      const float Qa =
          __int_as_float(__builtin_amdgcn_readlane(__float_as_int(qpq), 63));
      const float Qr =
          __int_as_float(__builtin_amdgcn_readlane(__float_as_int(qpx), 63));
      const float xv = fmaf(sa, scp.z, fmaf(lvp, scp.w, Qr)); // x_{c*16+15}
      sa             = fmaf(sa, scp.x, fmaf(lvp, scp.y, Qa)); // sa_{c*16+16}
      const int tl = ((c & 3) << 4) | 15;
      xacc = (lane == tl) ? xv : xacc;
    }

    __builtin_amdgcn_sched_barrier(0);
    STAGE_STORE(bi ^ 1);            // vmcnt wait lands here, after compute
    __syncthreads();

    if ((c & 3) == 3) {
      // 64 steps complete: transpose through LDS -> coalesced stores
      xbuf[wv][lane] = xacc;
      __syncthreads();
      const int tl2 = tid >> 3;
      const int iw  = tid & 7;
      const int t0  = (c + 1) * C - 64;
      xp[(size_t)(t0 + tl2) * HN + hb + ibase + iw] = xbuf[iw][tl2];
      // no trailing barrier needed: next xbuf write is 4 chunk-barriers away
    }
  }

#undef STAGE_LOAD
#undef STAGE_STORE

  sop[(size_t)(hb + i) * N_DIM + lane] = s;
}

extern "C" void kernel_launch(void* const* d_in, const int* in_sizes, int n_in,
                              void* d_out, int out_size, void* d_ws, size_t ws_size,
                              hipStream_t stream) {
  // setup_inputs order: seq_length(int,1), r, w, k, v, a, b, state2
  const float* r  = (const float*)d_in[1];
  const float* w  = (const float*)d_in[2];
  const float* k  = (const float*)d_in[3];
  const float* v  = (const float*)d_in[4];
  const float* a  = (const float*)d_in[5];
  const float* b  = (const float*)d_in[6];
  const float* s0 = (const float*)d_in[7];
  float* x    = (float*)d_out;                       // [T,H,1,N] flat
  float* sout = x + (size_t)T_LEN * H_HEADS * N_DIM; // [H,N,N]
  float* scw  = (float*)d_ws;                        // 2MB: [H][T][4] scalars

  wkv7_pre<<<dim3(T_LEN * H_HEADS / 4), dim3(256), 0, stream>>>(r, k, a, b, scw);
  wkv7_scan<<<dim3(NB), dim3(BT), 0, stream>>>(r, w, k, v, a, b, s0, x, sout, scw);
}